// Round 1
// baseline (3574.516 us; speedup 1.0000x reference)
//
#include <hip/hip_runtime.h>

// Problem constants (from reference)
constexpr int DIM     = 64;
constexpr int N_USERS = 100000;
constexpr int N_ITEMS = 50000;
constexpr int N_CATS  = 1000;
constexpr int NE_UI   = 2000000;
constexpr int NE_UU   = 1000000;
constexpr int NE_IC   = 150000;
constexpr int N_LAYERS = 3;

// SpMM: out[rows[e], :] += vals[e] * H[cols[e], :]
// One 64-lane wave per edge; lane = feature dim. Gather + atomic scatter are
// both 256B contiguous per wave (fully coalesced).
__global__ void spmm_edges(const int* __restrict__ rows, const int* __restrict__ cols,
                           const float* __restrict__ vals, const float* __restrict__ H,
                           float* __restrict__ out, int ne) {
    int tid  = blockIdx.x * blockDim.x + threadIdx.x;
    int e    = tid >> 6;
    int lane = threadIdx.x & 63;
    if (e >= ne) return;
    int   r = rows[e];
    int   c = cols[e];
    float v = vals[e];
    float x = v * H[(size_t)c * DIM + lane];
    unsafeAtomicAdd(&out[(size_t)r * DIM + lane], x);
}

__global__ void accum_kernel(float* __restrict__ sum, const float* __restrict__ h, int n) {
    int i = blockIdx.x * blockDim.x + threadIdx.x;
    int stride = gridDim.x * blockDim.x;
    for (; i < n; i += stride) sum[i] += h[i];
}

__global__ void scale_kernel(float* __restrict__ p, int n, float s) {
    int i = blockIdx.x * blockDim.x + threadIdx.x;
    int stride = gridDim.x * blockDim.x;
    for (; i < n; i += stride) p[i] *= s;
}

static inline int spmm_grid(int ne) {
    // ne waves, 4 waves (256 threads) per block
    return (ne + 3) / 4;
}

extern "C" void kernel_launch(void* const* d_in, const int* in_sizes, int n_in,
                              void* d_out, int out_size, void* d_ws, size_t ws_size,
                              hipStream_t stream) {
    const float* user_emb = (const float*)d_in[0];
    const float* item_emb = (const float*)d_in[1];
    const float* cat_emb  = (const float*)d_in[2];
    const float* ui_vals  = (const float*)d_in[3];
    const float* iu_vals  = (const float*)d_in[4];
    const float* uu_vals  = (const float*)d_in[5];
    const float* ic_vals  = (const float*)d_in[6];
    const float* ci_vals  = (const float*)d_in[7];
    const int*   ui_rows  = (const int*)d_in[8];
    const int*   ui_cols  = (const int*)d_in[9];
    const int*   iu_rows  = (const int*)d_in[10];
    const int*   iu_cols  = (const int*)d_in[11];
    const int*   uu_rows  = (const int*)d_in[12];
    const int*   uu_cols  = (const int*)d_in[13];
    const int*   ic_rows  = (const int*)d_in[14];
    const int*   ic_cols  = (const int*)d_in[15];
    const int*   ci_rows  = (const int*)d_in[16];
    const int*   ci_cols  = (const int*)d_in[17];

    constexpr size_t NU = (size_t)N_USERS * DIM;   // 6,400,000
    constexpr size_t NI = (size_t)N_ITEMS * DIM;   // 3,200,000
    constexpr size_t NC = (size_t)N_CATS  * DIM;   //    64,000

    // Workspace layout: double-buffered h_u, h_i, h_c (19,328,000 floats = 77.3 MB)
    float* ws = (float*)d_ws;
    float* h_u[2] = { ws,                 ws + NU };
    float* h_i[2] = { ws + 2*NU,          ws + 2*NU + NI };
    float* h_c[2] = { ws + 2*NU + 2*NI,   ws + 2*NU + 2*NI + NC };

    // Output layout: sum_u | sum_i | h_c
    float* sum_u = (float*)d_out;
    float* sum_i = sum_u + NU;
    float* out_c = sum_i + NI;

    // init: h = emb; sum = emb (layer-0 contribution)
    hipMemcpyAsync(h_u[0], user_emb, NU * sizeof(float), hipMemcpyDeviceToDevice, stream);
    hipMemcpyAsync(h_i[0], item_emb, NI * sizeof(float), hipMemcpyDeviceToDevice, stream);
    hipMemcpyAsync(h_c[0], cat_emb,  NC * sizeof(float), hipMemcpyDeviceToDevice, stream);
    hipMemcpyAsync(sum_u,  user_emb, NU * sizeof(float), hipMemcpyDeviceToDevice, stream);
    hipMemcpyAsync(sum_i,  item_emb, NI * sizeof(float), hipMemcpyDeviceToDevice, stream);

    const int blk = 256;
    const int ew_grid = 2048;  // grid-stride elementwise

    int cur = 0;
    for (int l = 0; l < N_LAYERS; ++l) {
        int nxt = cur ^ 1;
        hipMemsetAsync(h_u[nxt], 0, NU * sizeof(float), stream);
        hipMemsetAsync(h_i[nxt], 0, NI * sizeof(float), stream);
        hipMemsetAsync(h_c[nxt], 0, NC * sizeof(float), stream);

        // new_h_u = ui @ h_i + uu @ h_u
        spmm_edges<<<spmm_grid(NE_UI), blk, 0, stream>>>(ui_rows, ui_cols, ui_vals, h_i[cur], h_u[nxt], NE_UI);
        spmm_edges<<<spmm_grid(NE_UU), blk, 0, stream>>>(uu_rows, uu_cols, uu_vals, h_u[cur], h_u[nxt], NE_UU);
        // new_h_i = iu @ h_u + ic @ h_c
        spmm_edges<<<spmm_grid(NE_UI), blk, 0, stream>>>(iu_rows, iu_cols, iu_vals, h_u[cur], h_i[nxt], NE_UI);
        spmm_edges<<<spmm_grid(NE_IC), blk, 0, stream>>>(ic_rows, ic_cols, ic_vals, h_c[cur], h_i[nxt], NE_IC);
        // new_h_c = ci @ h_i
        spmm_edges<<<spmm_grid(NE_IC), blk, 0, stream>>>(ci_rows, ci_cols, ci_vals, h_i[cur], h_c[nxt], NE_IC);

        // sums
        accum_kernel<<<ew_grid, blk, 0, stream>>>(sum_u, h_u[nxt], (int)NU);
        accum_kernel<<<ew_grid, blk, 0, stream>>>(sum_i, h_i[nxt], (int)NI);

        cur = nxt;
    }

    const float inv = 1.0f / (N_LAYERS + 1);
    scale_kernel<<<ew_grid, blk, 0, stream>>>(sum_u, (int)NU, inv);
    scale_kernel<<<ew_grid, blk, 0, stream>>>(sum_i, (int)NI, inv);
    hipMemcpyAsync(out_c, h_c[cur], NC * sizeof(float), hipMemcpyDeviceToDevice, stream);
}

// Round 3
// 2343.690 us; speedup vs baseline: 1.5252x; 1.5252x over previous
//
#include <hip/hip_runtime.h>

// Problem constants (from reference)
constexpr int DIM      = 64;
constexpr int N_USERS  = 100000;
constexpr int N_ITEMS  = 50000;
constexpr int N_CATS   = 1000;
constexpr int NE_UI    = 2000000;
constexpr int NE_UU    = 1000000;
constexpr int NE_IC    = 150000;
constexpr int N_LAYERS = 3;

// ---------------- CSR build ----------------

__global__ void hist_kernel(const int* __restrict__ rows, int* __restrict__ counts, int ne) {
    int i = blockIdx.x * blockDim.x + threadIdx.x;
    int st = gridDim.x * blockDim.x;
    for (; i < ne; i += st) atomicAdd(&counts[rows[i]], 1);
}

constexpr int SCAN_BLK   = 256;
constexpr int SCAN_ELEMS = 8;
constexpr int SCAN_TILE  = SCAN_BLK * SCAN_ELEMS;  // 2048

// exclusive scan within tiles; per-tile totals to tile_sums. In-place safe
// (each thread reads its own 8 elems into regs before any write).
__global__ void scan_pass1(const int* __restrict__ in, int* __restrict__ out,
                           int* __restrict__ tile_sums, int n) {
    __shared__ int lds[SCAN_BLK];
    int base = blockIdx.x * SCAN_TILE + threadIdx.x * SCAN_ELEMS;
    int v[SCAN_ELEMS];
    int s = 0;
#pragma unroll
    for (int k = 0; k < SCAN_ELEMS; ++k) {
        int idx = base + k;
        v[k] = (idx < n) ? in[idx] : 0;
        s += v[k];
    }
    lds[threadIdx.x] = s;
    __syncthreads();
    for (int off = 1; off < SCAN_BLK; off <<= 1) {
        int t = (threadIdx.x >= (unsigned)off) ? lds[threadIdx.x - off] : 0;
        __syncthreads();
        lds[threadIdx.x] += t;
        __syncthreads();
    }
    if (threadIdx.x == SCAN_BLK - 1) tile_sums[blockIdx.x] = lds[SCAN_BLK - 1];
    int run = (threadIdx.x == 0) ? 0 : lds[threadIdx.x - 1];
#pragma unroll
    for (int k = 0; k < SCAN_ELEMS; ++k) {
        int idx = base + k;
        if (idx < n) out[idx] = run;
        run += v[k];
    }
}

// single block: exclusive scan of tile_sums (m <= 256); writes grand total to *total_out
__global__ void scan_pass2(int* __restrict__ tile_sums, int m, int* __restrict__ total_out) {
    __shared__ int lds[256];
    int tid = threadIdx.x;
    int v = (tid < m) ? tile_sums[tid] : 0;
    lds[tid] = v;
    __syncthreads();
    for (int off = 1; off < 256; off <<= 1) {
        int t = (tid >= off) ? lds[tid - off] : 0;
        __syncthreads();
        lds[tid] += t;
        __syncthreads();
    }
    if (tid < m) tile_sums[tid] = lds[tid] - v;  // exclusive
    if (tid == 255 && total_out) *total_out = lds[255];
}

__global__ void scan_pass3(int* __restrict__ out, const int* __restrict__ tile_sums, int n) {
    int add = tile_sums[blockIdx.x];
#pragma unroll
    for (int k = 0; k < SCAN_ELEMS; ++k) {
        int idx = blockIdx.x * SCAN_TILE + k * SCAN_BLK + threadIdx.x;
        if (idx < n) out[idx] += add;
    }
}

__global__ void scatter_kernel(const int* __restrict__ rows, const int* __restrict__ cols,
                               const float* __restrict__ vals, int* __restrict__ offs,
                               int2* __restrict__ edges, int ne) {
    int i = blockIdx.x * blockDim.x + threadIdx.x;
    int st = gridDim.x * blockDim.x;
    for (; i < ne; i += st) {
        int r = rows[i];
        int pos = atomicAdd(&offs[r], 1);
        edges[pos] = make_int2(cols[i], __float_as_int(vals[i]));
    }
}

// ---------------- pull-style fused layer kernels ----------------

__device__ __forceinline__ float row_gather(const int* __restrict__ ptr,
                                            const int2* __restrict__ edges,
                                            const float* __restrict__ H,
                                            int r, int lane) {
    int s = ptr[r], e = ptr[r + 1];
    float acc = 0.f;
    for (int j = s; j < e; ++j) {
        int2 ed = edges[j];
        acc = fmaf(__int_as_float(ed.y), H[(size_t)ed.x * DIM + lane], acc);
    }
    return acc;
}

// dest row = two SpMMs fused; also fuses running-sum accumulate and final scale
__global__ void layer_two(const int* __restrict__ pA, const int2* __restrict__ eA, const float* __restrict__ HA,
                          const int* __restrict__ pB, const int2* __restrict__ eB, const float* __restrict__ HB,
                          float* __restrict__ h_out, float* __restrict__ sum,
                          int nrows, float scale, int last) {
    int wid  = (blockIdx.x * blockDim.x + threadIdx.x) >> 6;
    int lane = threadIdx.x & 63;
    if (wid >= nrows) return;
    float acc = row_gather(pA, eA, HA, wid, lane) + row_gather(pB, eB, HB, wid, lane);
    size_t o = (size_t)wid * DIM + lane;
    if (last) {
        sum[o] = (sum[o] + acc) * scale;
    } else {
        h_out[o] = acc;
        sum[o] += acc;
    }
}

__global__ void layer_one(const int* __restrict__ p, const int2* __restrict__ e,
                          const float* __restrict__ H, float* __restrict__ out, int nrows) {
    int wid  = (blockIdx.x * blockDim.x + threadIdx.x) >> 6;
    int lane = threadIdx.x & 63;
    if (wid >= nrows) return;
    out[(size_t)wid * DIM + lane] = row_gather(p, e, H, wid, lane);
}

// ---------------- fallback (round-1 push-atomic path) ----------------

__global__ void spmm_edges(const int* __restrict__ rows, const int* __restrict__ cols,
                           const float* __restrict__ vals, const float* __restrict__ H,
                           float* __restrict__ out, int ne) {
    int tid  = blockIdx.x * blockDim.x + threadIdx.x;
    int e    = tid >> 6;
    int lane = threadIdx.x & 63;
    if (e >= ne) return;
    float x = vals[e] * H[(size_t)cols[e] * DIM + lane];
    unsafeAtomicAdd(&out[(size_t)rows[e] * DIM + lane], x);
}

__global__ void accum_kernel(float* __restrict__ sum, const float* __restrict__ h, int n) {
    int i = blockIdx.x * blockDim.x + threadIdx.x;
    int st = gridDim.x * blockDim.x;
    for (; i < n; i += st) sum[i] += h[i];
}

__global__ void scale_kernel(float* __restrict__ p, int n, float s) {
    int i = blockIdx.x * blockDim.x + threadIdx.x;
    int st = gridDim.x * blockDim.x;
    for (; i < n; i += st) p[i] *= s;
}

// ---------------- host ----------------

static void build_csr(const int* rows, const int* cols, const float* vals, int ne, int n_out,
                      int* ptr, int2* edges, int* offs, int* tile_sums, hipStream_t stream) {
    hipMemsetAsync(ptr, 0, (size_t)(n_out + 1) * sizeof(int), stream);
    int g = (ne + 255) / 256;
    if (g > 4096) g = 4096;
    hist_kernel<<<g, 256, 0, stream>>>(rows, ptr, ne);
    int tiles = (n_out + SCAN_TILE - 1) / SCAN_TILE;
    scan_pass1<<<tiles, SCAN_BLK, 0, stream>>>(ptr, ptr, tile_sums, n_out);
    scan_pass2<<<1, 256, 0, stream>>>(tile_sums, tiles, ptr + n_out);
    scan_pass3<<<tiles, SCAN_BLK, 0, stream>>>(ptr, tile_sums, n_out);
    hipMemcpyAsync(offs, ptr, (size_t)n_out * sizeof(int), hipMemcpyDeviceToDevice, stream);
    scatter_kernel<<<g, 256, 0, stream>>>(rows, cols, vals, offs, edges, ne);
}

extern "C" void kernel_launch(void* const* d_in, const int* in_sizes, int n_in,
                              void* d_out, int out_size, void* d_ws, size_t ws_size,
                              hipStream_t stream) {
    const float* user_emb = (const float*)d_in[0];
    const float* item_emb = (const float*)d_in[1];
    const float* cat_emb  = (const float*)d_in[2];
    const float* ui_vals  = (const float*)d_in[3];
    const float* iu_vals  = (const float*)d_in[4];
    const float* uu_vals  = (const float*)d_in[5];
    const float* ic_vals  = (const float*)d_in[6];
    const float* ci_vals  = (const float*)d_in[7];
    const int*   ui_rows  = (const int*)d_in[8];
    const int*   ui_cols  = (const int*)d_in[9];
    const int*   iu_rows  = (const int*)d_in[10];
    const int*   iu_cols  = (const int*)d_in[11];
    const int*   uu_rows  = (const int*)d_in[12];
    const int*   uu_cols  = (const int*)d_in[13];
    const int*   ic_rows  = (const int*)d_in[14];
    const int*   ic_cols  = (const int*)d_in[15];
    const int*   ci_rows  = (const int*)d_in[16];
    const int*   ci_cols  = (const int*)d_in[17];

    constexpr size_t NU = (size_t)N_USERS * DIM;  // 6,400,000
    constexpr size_t NI = (size_t)N_ITEMS * DIM;  // 3,200,000
    constexpr size_t NC = (size_t)N_CATS  * DIM;  //    64,000

    float* ws = (float*)d_ws;
    float* h_u[2] = { ws,               ws + NU };
    float* h_i[2] = { ws + 2 * NU,      ws + 2 * NU + NI };
    float* h_c[2] = { ws + 2 * NU + 2 * NI, ws + 2 * NU + 2 * NI + NC };

    float* sum_u = (float*)d_out;
    float* sum_i = sum_u + NU;
    float* out_c = sum_i + NI;

    const int blk = 256;
    const float inv = 1.0f / (N_LAYERS + 1);

    // ---- CSR workspace layout: explicit bump allocator (int units) ----
    // Double buffers occupy [0, P).
    constexpr size_t P = 2 * NU + 2 * NI + 2 * NC;  // 19,328,000 ints
    int* ib = (int*)d_ws;
    size_t off = P;
    int* ui_ptr = ib + off;  off += (size_t)N_USERS + 1;   // 100,001
    int* iu_ptr = ib + off;  off += (size_t)N_ITEMS + 1;   //  50,001
    int* uu_ptr = ib + off;  off += (size_t)N_USERS + 1;   // 100,001
    int* ic_ptr = ib + off;  off += (size_t)N_ITEMS + 1;   //  50,001
    int* ci_ptr = ib + off;  off += (size_t)N_CATS  + 1;   //   1,001
    off = (off + 1) & ~(size_t)1;                          // even-align for int2
    int2* ui_e = (int2*)(ib + off);  off += 2 * (size_t)NE_UI;
    int2* iu_e = (int2*)(ib + off);  off += 2 * (size_t)NE_UI;
    int2* uu_e = (int2*)(ib + off);  off += 2 * (size_t)NE_UU;
    int2* ic_e = (int2*)(ib + off);  off += 2 * (size_t)NE_IC;
    int2* ci_e = (int2*)(ib + off);  off += 2 * (size_t)NE_IC;
    int* offs      = ib + off;  off += (size_t)N_USERS + 1;
    int* tile_sums = ib + off;  off += 256;
    size_t needed_bytes = off * sizeof(int);  // ~121.3 MB

    // init: h = emb; sum = emb (layer-0 contribution)
    hipMemcpyAsync(h_u[0], user_emb, NU * sizeof(float), hipMemcpyDeviceToDevice, stream);
    hipMemcpyAsync(h_i[0], item_emb, NI * sizeof(float), hipMemcpyDeviceToDevice, stream);
    hipMemcpyAsync(h_c[0], cat_emb,  NC * sizeof(float), hipMemcpyDeviceToDevice, stream);
    hipMemcpyAsync(sum_u,  user_emb, NU * sizeof(float), hipMemcpyDeviceToDevice, stream);
    hipMemcpyAsync(sum_i,  item_emb, NI * sizeof(float), hipMemcpyDeviceToDevice, stream);

    if (ws_size >= needed_bytes) {
        // ---- pull path: build CSR once per launch ----
        build_csr(ui_rows, ui_cols, ui_vals, NE_UI, N_USERS, ui_ptr, ui_e, offs, tile_sums, stream);
        build_csr(iu_rows, iu_cols, iu_vals, NE_UI, N_ITEMS, iu_ptr, iu_e, offs, tile_sums, stream);
        build_csr(uu_rows, uu_cols, uu_vals, NE_UU, N_USERS, uu_ptr, uu_e, offs, tile_sums, stream);
        build_csr(ic_rows, ic_cols, ic_vals, NE_IC, N_ITEMS, ic_ptr, ic_e, offs, tile_sums, stream);
        build_csr(ci_rows, ci_cols, ci_vals, NE_IC, N_CATS,  ci_ptr, ci_e, offs, tile_sums, stream);

        int gu = (N_USERS * 64 + blk - 1) / blk;  // 4 waves (rows) per block
        int gi = (N_ITEMS * 64 + blk - 1) / blk;
        int gc = (N_CATS  * 64 + blk - 1) / blk;

        int cur = 0;
        for (int l = 0; l < N_LAYERS; ++l) {
            int nxt = cur ^ 1;
            int last = (l == N_LAYERS - 1);
            layer_two<<<gu, blk, 0, stream>>>(ui_ptr, ui_e, h_i[cur], uu_ptr, uu_e, h_u[cur],
                                              h_u[nxt], sum_u, N_USERS, inv, last);
            layer_two<<<gi, blk, 0, stream>>>(iu_ptr, iu_e, h_u[cur], ic_ptr, ic_e, h_c[cur],
                                              h_i[nxt], sum_i, N_ITEMS, inv, last);
            layer_one<<<gc, blk, 0, stream>>>(ci_ptr, ci_e, h_i[cur],
                                              last ? out_c : h_c[nxt], N_CATS);
            cur = nxt;
        }
    } else {
        // ---- fallback: round-1 push-atomic path ----
        const int ew_grid = 2048;
        int cur = 0;
        for (int l = 0; l < N_LAYERS; ++l) {
            int nxt = cur ^ 1;
            hipMemsetAsync(h_u[nxt], 0, NU * sizeof(float), stream);
            hipMemsetAsync(h_i[nxt], 0, NI * sizeof(float), stream);
            hipMemsetAsync(h_c[nxt], 0, NC * sizeof(float), stream);
            spmm_edges<<<(NE_UI + 3) / 4, blk, 0, stream>>>(ui_rows, ui_cols, ui_vals, h_i[cur], h_u[nxt], NE_UI);
            spmm_edges<<<(NE_UU + 3) / 4, blk, 0, stream>>>(uu_rows, uu_cols, uu_vals, h_u[cur], h_u[nxt], NE_UU);
            spmm_edges<<<(NE_UI + 3) / 4, blk, 0, stream>>>(iu_rows, iu_cols, iu_vals, h_u[cur], h_i[nxt], NE_UI);
            spmm_edges<<<(NE_IC + 3) / 4, blk, 0, stream>>>(ic_rows, ic_cols, ic_vals, h_c[cur], h_i[nxt], NE_IC);
            spmm_edges<<<(NE_IC + 3) / 4, blk, 0, stream>>>(ci_rows, ci_cols, ci_vals, h_i[cur], h_c[nxt], NE_IC);
            accum_kernel<<<ew_grid, blk, 0, stream>>>(sum_u, h_u[nxt], (int)NU);
            accum_kernel<<<ew_grid, blk, 0, stream>>>(sum_i, h_i[nxt], (int)NI);
            cur = nxt;
        }
        scale_kernel<<<ew_grid, blk, 0, stream>>>(sum_u, (int)NU, inv);
        scale_kernel<<<ew_grid, blk, 0, stream>>>(sum_i, (int)NI, inv);
        hipMemcpyAsync(out_c, h_c[cur], NC * sizeof(float), hipMemcpyDeviceToDevice, stream);
    }
}

// Round 4
// 1408.390 us; speedup vs baseline: 2.5380x; 1.6641x over previous
//
#include <hip/hip_runtime.h>

// Problem constants (from reference)
constexpr int DIM      = 64;
constexpr int N_USERS  = 100000;
constexpr int N_ITEMS  = 50000;
constexpr int N_CATS   = 1000;
constexpr int NE_UI    = 2000000;
constexpr int NE_UU    = 1000000;
constexpr int NE_IC    = 150000;
constexpr int N_LAYERS = 3;

// ---------------- CSR build ----------------

__global__ void hist_kernel(const int* __restrict__ rows, int* __restrict__ counts, int ne) {
    int i = blockIdx.x * blockDim.x + threadIdx.x;
    int st = gridDim.x * blockDim.x;
    for (; i < ne; i += st) atomicAdd(&counts[rows[i]], 1);
}

constexpr int SCAN_BLK   = 256;
constexpr int SCAN_ELEMS = 8;
constexpr int SCAN_TILE  = SCAN_BLK * SCAN_ELEMS;  // 2048

__global__ void scan_pass1(const int* __restrict__ in, int* __restrict__ out,
                           int* __restrict__ tile_sums, int n) {
    __shared__ int lds[SCAN_BLK];
    int base = blockIdx.x * SCAN_TILE + threadIdx.x * SCAN_ELEMS;
    int v[SCAN_ELEMS];
    int s = 0;
#pragma unroll
    for (int k = 0; k < SCAN_ELEMS; ++k) {
        int idx = base + k;
        v[k] = (idx < n) ? in[idx] : 0;
        s += v[k];
    }
    lds[threadIdx.x] = s;
    __syncthreads();
    for (int off = 1; off < SCAN_BLK; off <<= 1) {
        int t = (threadIdx.x >= (unsigned)off) ? lds[threadIdx.x - off] : 0;
        __syncthreads();
        lds[threadIdx.x] += t;
        __syncthreads();
    }
    if (threadIdx.x == SCAN_BLK - 1) tile_sums[blockIdx.x] = lds[SCAN_BLK - 1];
    int run = (threadIdx.x == 0) ? 0 : lds[threadIdx.x - 1];
#pragma unroll
    for (int k = 0; k < SCAN_ELEMS; ++k) {
        int idx = base + k;
        if (idx < n) out[idx] = run;
        run += v[k];
    }
}

__global__ void scan_pass2(int* __restrict__ tile_sums, int m, int* __restrict__ total_out) {
    __shared__ int lds[256];
    int tid = threadIdx.x;
    int v = (tid < m) ? tile_sums[tid] : 0;
    lds[tid] = v;
    __syncthreads();
    for (int off = 1; off < 256; off <<= 1) {
        int t = (tid >= off) ? lds[tid - off] : 0;
        __syncthreads();
        lds[tid] += t;
        __syncthreads();
    }
    if (tid < m) tile_sums[tid] = lds[tid] - v;  // exclusive
    if (tid == 255 && total_out) *total_out = lds[255];
}

__global__ void scan_pass3(int* __restrict__ out, const int* __restrict__ tile_sums, int n) {
    int add = tile_sums[blockIdx.x];
#pragma unroll
    for (int k = 0; k < SCAN_ELEMS; ++k) {
        int idx = blockIdx.x * SCAN_TILE + k * SCAN_BLK + threadIdx.x;
        if (idx < n) out[idx] += add;
    }
}

__global__ void scatter_kernel(const int* __restrict__ rows, const int* __restrict__ cols,
                               const float* __restrict__ vals, int* __restrict__ offs,
                               int2* __restrict__ edges, int ne) {
    int i = blockIdx.x * blockDim.x + threadIdx.x;
    int st = gridDim.x * blockDim.x;
    for (; i < ne; i += st) {
        int r = rows[i];
        int pos = atomicAdd(&offs[r], 1);
        edges[pos] = make_int2(cols[i], __float_as_int(vals[i]));
    }
}

// ---------------- pull-style fused layer kernels ----------------
// Wave layout: 4 edge-groups (grp = lane>>4) x 16 lanes (sub = lane&15) x float4.
// Each group walks every 4th edge of the row -> 4 independent gather streams
// in flight per wave; each 16-lane group's H-load is one 256B coalesced read.

__device__ __forceinline__ void gather4(const int* __restrict__ ptr,
                                        const int2* __restrict__ edges,
                                        const float* __restrict__ H,
                                        int r, int grp, int sub, float4& acc) {
    int s = ptr[r], e = ptr[r + 1];
    for (int j = s + grp; j < e; j += 4) {
        int2 ed = edges[j];
        float4 hv = *reinterpret_cast<const float4*>(H + (size_t)ed.x * DIM + sub * 4);
        float w = __int_as_float(ed.y);
        acc.x = fmaf(w, hv.x, acc.x);
        acc.y = fmaf(w, hv.y, acc.y);
        acc.z = fmaf(w, hv.z, acc.z);
        acc.w = fmaf(w, hv.w, acc.w);
    }
}

__device__ __forceinline__ void xgroup_reduce(float4& a) {
#pragma unroll
    for (int m = 16; m <= 32; m <<= 1) {
        a.x += __shfl_xor(a.x, m);
        a.y += __shfl_xor(a.y, m);
        a.z += __shfl_xor(a.z, m);
        a.w += __shfl_xor(a.w, m);
    }
}

__global__ void layer_two(const int* __restrict__ pA, const int2* __restrict__ eA, const float* __restrict__ HA,
                          const int* __restrict__ pB, const int2* __restrict__ eB, const float* __restrict__ HB,
                          float* __restrict__ h_out, float* __restrict__ sum,
                          int nrows, float scale, int last) {
    int wid  = (blockIdx.x * blockDim.x + threadIdx.x) >> 6;
    int lane = threadIdx.x & 63;
    if (wid >= nrows) return;
    int grp = lane >> 4, sub = lane & 15;
    float4 acc = make_float4(0.f, 0.f, 0.f, 0.f);
    gather4(pA, eA, HA, wid, grp, sub, acc);
    gather4(pB, eB, HB, wid, grp, sub, acc);
    xgroup_reduce(acc);  // all lanes now hold final acc for dims [sub*4, sub*4+4)
    size_t o = (size_t)wid * DIM + sub * 4;
    if (last) {
        if (grp == 0) {
            float4 sv = *reinterpret_cast<const float4*>(sum + o);
            sv.x = (sv.x + acc.x) * scale;
            sv.y = (sv.y + acc.y) * scale;
            sv.z = (sv.z + acc.z) * scale;
            sv.w = (sv.w + acc.w) * scale;
            *reinterpret_cast<float4*>(sum + o) = sv;
        }
    } else {
        if (grp == 0) {
            *reinterpret_cast<float4*>(h_out + o) = acc;
        } else if (grp == 1) {
            float4 sv = *reinterpret_cast<const float4*>(sum + o);
            sv.x += acc.x; sv.y += acc.y; sv.z += acc.z; sv.w += acc.w;
            *reinterpret_cast<float4*>(sum + o) = sv;
        }
    }
}

__global__ void layer_one(const int* __restrict__ p, const int2* __restrict__ e,
                          const float* __restrict__ H, float* __restrict__ out, int nrows) {
    int wid  = (blockIdx.x * blockDim.x + threadIdx.x) >> 6;
    int lane = threadIdx.x & 63;
    if (wid >= nrows) return;
    int grp = lane >> 4, sub = lane & 15;
    float4 acc = make_float4(0.f, 0.f, 0.f, 0.f);
    gather4(p, e, H, wid, grp, sub, acc);
    xgroup_reduce(acc);
    if (grp == 0)
        *reinterpret_cast<float4*>(out + (size_t)wid * DIM + sub * 4) = acc;
}

// ---------------- fallback (round-1 push-atomic path) ----------------

__global__ void spmm_edges(const int* __restrict__ rows, const int* __restrict__ cols,
                           const float* __restrict__ vals, const float* __restrict__ H,
                           float* __restrict__ out, int ne) {
    int tid  = blockIdx.x * blockDim.x + threadIdx.x;
    int e    = tid >> 6;
    int lane = threadIdx.x & 63;
    if (e >= ne) return;
    float x = vals[e] * H[(size_t)cols[e] * DIM + lane];
    unsafeAtomicAdd(&out[(size_t)rows[e] * DIM + lane], x);
}

__global__ void accum_kernel(float* __restrict__ sum, const float* __restrict__ h, int n) {
    int i = blockIdx.x * blockDim.x + threadIdx.x;
    int st = gridDim.x * blockDim.x;
    for (; i < n; i += st) sum[i] += h[i];
}

__global__ void scale_kernel(float* __restrict__ p, int n, float s) {
    int i = blockIdx.x * blockDim.x + threadIdx.x;
    int st = gridDim.x * blockDim.x;
    for (; i < n; i += st) p[i] *= s;
}

// ---------------- host ----------------

static void build_csr(const int* rows, const int* cols, const float* vals, int ne, int n_out,
                      int* ptr, int2* edges, int* offs, int* tile_sums, hipStream_t stream) {
    hipMemsetAsync(ptr, 0, (size_t)(n_out + 1) * sizeof(int), stream);
    int g = (ne + 255) / 256;
    if (g > 4096) g = 4096;
    hist_kernel<<<g, 256, 0, stream>>>(rows, ptr, ne);
    int tiles = (n_out + SCAN_TILE - 1) / SCAN_TILE;
    scan_pass1<<<tiles, SCAN_BLK, 0, stream>>>(ptr, ptr, tile_sums, n_out);
    scan_pass2<<<1, 256, 0, stream>>>(tile_sums, tiles, ptr + n_out);
    scan_pass3<<<tiles, SCAN_BLK, 0, stream>>>(ptr, tile_sums, n_out);
    hipMemcpyAsync(offs, ptr, (size_t)n_out * sizeof(int), hipMemcpyDeviceToDevice, stream);
    scatter_kernel<<<g, 256, 0, stream>>>(rows, cols, vals, offs, edges, ne);
}

extern "C" void kernel_launch(void* const* d_in, const int* in_sizes, int n_in,
                              void* d_out, int out_size, void* d_ws, size_t ws_size,
                              hipStream_t stream) {
    const float* user_emb = (const float*)d_in[0];
    const float* item_emb = (const float*)d_in[1];
    const float* cat_emb  = (const float*)d_in[2];
    const float* ui_vals  = (const float*)d_in[3];
    const float* iu_vals  = (const float*)d_in[4];
    const float* uu_vals  = (const float*)d_in[5];
    const float* ic_vals  = (const float*)d_in[6];
    const float* ci_vals  = (const float*)d_in[7];
    const int*   ui_rows  = (const int*)d_in[8];
    const int*   ui_cols  = (const int*)d_in[9];
    const int*   iu_rows  = (const int*)d_in[10];
    const int*   iu_cols  = (const int*)d_in[11];
    const int*   uu_rows  = (const int*)d_in[12];
    const int*   uu_cols  = (const int*)d_in[13];
    const int*   ic_rows  = (const int*)d_in[14];
    const int*   ic_cols  = (const int*)d_in[15];
    const int*   ci_rows  = (const int*)d_in[16];
    const int*   ci_cols  = (const int*)d_in[17];

    constexpr size_t NU = (size_t)N_USERS * DIM;  // 6,400,000
    constexpr size_t NI = (size_t)N_ITEMS * DIM;  // 3,200,000
    constexpr size_t NC = (size_t)N_CATS  * DIM;  //    64,000

    float* ws = (float*)d_ws;
    float* h_u[2] = { ws,               ws + NU };
    float* h_i[2] = { ws + 2 * NU,      ws + 2 * NU + NI };
    float* h_c[2] = { ws + 2 * NU + 2 * NI, ws + 2 * NU + 2 * NI + NC };

    float* sum_u = (float*)d_out;
    float* sum_i = sum_u + NU;
    float* out_c = sum_i + NI;

    const int blk = 256;
    const float inv = 1.0f / (N_LAYERS + 1);

    // ---- CSR workspace layout: explicit bump allocator (int units) ----
    constexpr size_t P = 2 * NU + 2 * NI + 2 * NC;  // 19,328,000 ints
    int* ib = (int*)d_ws;
    size_t off = P;
    int* ui_ptr = ib + off;  off += (size_t)N_USERS + 1;
    int* iu_ptr = ib + off;  off += (size_t)N_ITEMS + 1;
    int* uu_ptr = ib + off;  off += (size_t)N_USERS + 1;
    int* ic_ptr = ib + off;  off += (size_t)N_ITEMS + 1;
    int* ci_ptr = ib + off;  off += (size_t)N_CATS  + 1;
    off = (off + 1) & ~(size_t)1;                   // even-align for int2
    int2* ui_e = (int2*)(ib + off);  off += 2 * (size_t)NE_UI;
    int2* iu_e = (int2*)(ib + off);  off += 2 * (size_t)NE_UI;
    int2* uu_e = (int2*)(ib + off);  off += 2 * (size_t)NE_UU;
    int2* ic_e = (int2*)(ib + off);  off += 2 * (size_t)NE_IC;
    int2* ci_e = (int2*)(ib + off);  off += 2 * (size_t)NE_IC;
    int* offs      = ib + off;  off += (size_t)N_USERS + 1;
    int* tile_sums = ib + off;  off += 256;
    size_t needed_bytes = off * sizeof(int);  // ~121.3 MB

    // init: h = emb; sum = emb (layer-0 contribution)
    hipMemcpyAsync(h_u[0], user_emb, NU * sizeof(float), hipMemcpyDeviceToDevice, stream);
    hipMemcpyAsync(h_i[0], item_emb, NI * sizeof(float), hipMemcpyDeviceToDevice, stream);
    hipMemcpyAsync(h_c[0], cat_emb,  NC * sizeof(float), hipMemcpyDeviceToDevice, stream);
    hipMemcpyAsync(sum_u,  user_emb, NU * sizeof(float), hipMemcpyDeviceToDevice, stream);
    hipMemcpyAsync(sum_i,  item_emb, NI * sizeof(float), hipMemcpyDeviceToDevice, stream);

    if (ws_size >= needed_bytes) {
        // ---- pull path: build CSR once per launch ----
        build_csr(ui_rows, ui_cols, ui_vals, NE_UI, N_USERS, ui_ptr, ui_e, offs, tile_sums, stream);
        build_csr(iu_rows, iu_cols, iu_vals, NE_UI, N_ITEMS, iu_ptr, iu_e, offs, tile_sums, stream);
        build_csr(uu_rows, uu_cols, uu_vals, NE_UU, N_USERS, uu_ptr, uu_e, offs, tile_sums, stream);
        build_csr(ic_rows, ic_cols, ic_vals, NE_IC, N_ITEMS, ic_ptr, ic_e, offs, tile_sums, stream);
        build_csr(ci_rows, ci_cols, ci_vals, NE_IC, N_CATS,  ci_ptr, ci_e, offs, tile_sums, stream);

        int gu = (N_USERS * 64 + blk - 1) / blk;  // 4 rows (waves) per block
        int gi = (N_ITEMS * 64 + blk - 1) / blk;
        int gc = (N_CATS  * 64 + blk - 1) / blk;

        int cur = 0;
        for (int l = 0; l < N_LAYERS; ++l) {
            int nxt = cur ^ 1;
            int last = (l == N_LAYERS - 1);
            layer_two<<<gu, blk, 0, stream>>>(ui_ptr, ui_e, h_i[cur], uu_ptr, uu_e, h_u[cur],
                                              h_u[nxt], sum_u, N_USERS, inv, last);
            layer_two<<<gi, blk, 0, stream>>>(iu_ptr, iu_e, h_u[cur], ic_ptr, ic_e, h_c[cur],
                                              h_i[nxt], sum_i, N_ITEMS, inv, last);
            layer_one<<<gc, blk, 0, stream>>>(ci_ptr, ci_e, h_i[cur],
                                              last ? out_c : h_c[nxt], N_CATS);
            cur = nxt;
        }
    } else {
        // ---- fallback: round-1 push-atomic path ----
        const int ew_grid = 2048;
        int cur = 0;
        for (int l = 0; l < N_LAYERS; ++l) {
            int nxt = cur ^ 1;
            hipMemsetAsync(h_u[nxt], 0, NU * sizeof(float), stream);
            hipMemsetAsync(h_i[nxt], 0, NI * sizeof(float), stream);
            hipMemsetAsync(h_c[nxt], 0, NC * sizeof(float), stream);
            spmm_edges<<<(NE_UI + 3) / 4, blk, 0, stream>>>(ui_rows, ui_cols, ui_vals, h_i[cur], h_u[nxt], NE_UI);
            spmm_edges<<<(NE_UU + 3) / 4, blk, 0, stream>>>(uu_rows, uu_cols, uu_vals, h_u[cur], h_u[nxt], NE_UU);
            spmm_edges<<<(NE_UI + 3) / 4, blk, 0, stream>>>(iu_rows, iu_cols, iu_vals, h_u[cur], h_i[nxt], NE_UI);
            spmm_edges<<<(NE_IC + 3) / 4, blk, 0, stream>>>(ic_rows, ic_cols, ic_vals, h_c[cur], h_i[nxt], NE_IC);
            spmm_edges<<<(NE_IC + 3) / 4, blk, 0, stream>>>(ci_rows, ci_cols, ci_vals, h_i[cur], h_c[nxt], NE_IC);
            accum_kernel<<<ew_grid, blk, 0, stream>>>(sum_u, h_u[nxt], (int)NU);
            accum_kernel<<<ew_grid, blk, 0, stream>>>(sum_i, h_i[nxt], (int)NI);
            cur = nxt;
        }
        scale_kernel<<<ew_grid, blk, 0, stream>>>(sum_u, (int)NU, inv);
        scale_kernel<<<ew_grid, blk, 0, stream>>>(sum_i, (int)NI, inv);
        hipMemcpyAsync(out_c, h_c[cur], NC * sizeof(float), hipMemcpyDeviceToDevice, stream);
    }
}